// Round 1
// 332.513 us; speedup vs baseline: 1.0032x; 1.0032x over previous
//
#include <hip/hip_runtime.h>

// Complex 2x nearest-neighbor upsample, PLANAR output layout:
//   out = stack([y.real, y.imag]) -> (2, B, 2H, 2W, C) float32
//
// Inverted mapping vs previous version: ONE THREAD PER INPUT float4.
// Each thread: 2 nontemporal loads (re, im) + 8 nontemporal stores
// (2x2 spatial quad x 2 planes). Every input float4 is touched exactly
// once globally (pure single-pass read stream, no L2-dedup reliance);
// store stream is full-line NT writes. Traffic = 134 MB read + 537 MB
// write = the structural minimum.

#define BB 16
#define HH 128
#define WW 128
#define CC 64
#define OH (2 * HH)   // 256
#define OW (2 * WW)   // 256

typedef float vfloat4 __attribute__((ext_vector_type(4)));

__global__ __launch_bounds__(256) void complex_upsample2x_quad(
    const float* __restrict__ x_re,
    const float* __restrict__ x_im,
    float* __restrict__ out,
    unsigned in_vec4,      // B*H*W*C/4   = 4,194,304
    unsigned plane_vec4,   // B*OH*OW*C/4 = 16,777,216
    int n_planes) {
    const unsigned t = blockIdx.x * blockDim.x + threadIdx.x;
    if (t >= in_vec4) return;

    // t = (((b*H + hi)*W + wi)*C)/4 + g  with g in [0,16)
    const unsigned g  = t & (CC / 4 - 1);   // channel group
    const unsigned ip = t >> 4;             // input pixel
    const unsigned wi = ip & (WW - 1);
    const unsigned r  = ip >> 7;            // log2(W)=7
    const unsigned hi = r & (HH - 1);
    const unsigned b  = r >> 7;             // log2(H)=7

    // output float4 index of (b, 2*hi, 2*wi, 4*g):
    //   b*(OH*OW*C/4) + 2*hi*(OW*C/4) + 2*wi*(C/4) + g
    // = b<<20 | hi<<13 | wi<<5 | g
    const unsigned q00 = (b << 20) | (hi << 13) | (wi << 5) | g;
    const unsigned q01 = q00 + (CC / 4);        // w+1:  +16
    const unsigned q10 = q00 + (OW * CC / 4);   // h+1:  +4096
    const unsigned q11 = q10 + (CC / 4);

    // Issue both loads up front (independent, in flight together).
    const vfloat4 re = __builtin_nontemporal_load(
        reinterpret_cast<const vfloat4*>(x_re) + t);
    const vfloat4 im = __builtin_nontemporal_load(
        reinterpret_cast<const vfloat4*>(x_im) + t);

    vfloat4* outv = reinterpret_cast<vfloat4*>(out);
    __builtin_nontemporal_store(re, outv + q00);
    __builtin_nontemporal_store(re, outv + q01);
    __builtin_nontemporal_store(re, outv + q10);
    __builtin_nontemporal_store(re, outv + q11);

    if (n_planes == 2) {
        vfloat4* o2 = outv + plane_vec4;
        __builtin_nontemporal_store(im, o2 + q00);
        __builtin_nontemporal_store(im, o2 + q01);
        __builtin_nontemporal_store(im, o2 + q10);
        __builtin_nontemporal_store(im, o2 + q11);
    }
}

extern "C" void kernel_launch(void* const* d_in, const int* in_sizes, int n_in,
                              void* d_out, int out_size, void* d_ws, size_t ws_size,
                              hipStream_t stream) {
    const float* x_re = (const float*)d_in[0];
    const float* x_im = (const float*)d_in[1];
    float* out = (float*)d_out;

    const unsigned in_elems    = BB * HH * WW * CC;           // 16,777,216
    const unsigned plane_elems = BB * OH * OW * CC;           // 67,108,864
    const int n_planes = (out_size >= (int64_t)2 * plane_elems) ? 2 : 1;

    const unsigned in_vec4    = in_elems / 4;                 // 4,194,304
    const unsigned plane_vec4 = plane_elems / 4;              // 16,777,216

    const int block = 256;
    const unsigned grid = (in_vec4 + block - 1) / block;      // 16,384 blocks
    complex_upsample2x_quad<<<grid, block, 0, stream>>>(x_re, x_im, out,
                                                        in_vec4, plane_vec4,
                                                        n_planes);
}